// Round 5
// baseline (622.470 us; speedup 1.0000x reference)
//
#include <hip/hip_runtime.h>

// Problem constants (match reference)
#define HH 256
#define WW 256
#define HWSZ (HH * WW)
#define BB 32
#define CC 18
#define NBLK 3

// Output: gen_poses [2,32,18,256,256] + step_poses [2,32,18,256,256]
// = 150,994,944 f32 = 37,748,736 float4.
// Fill partition: 2048 blocks x 256 thr = 524,288 threads x exactly 72 float4.
#define FILL_BLOCKS 2048
#define FILL_THREADS 256
#define FILL_ITERS 72   // 2048*256*72 == 37,748,736

// Native clang vector type — __builtin_nontemporal_store requires this
// (HIP's float4 is a class and is rejected by the builtin).
typedef float v4f __attribute__((ext_vector_type(4)));

// ---------------------------------------------------------------------------
// Tuned zero-fill: exact uniform partition (no bounds checks), unrolled,
// nontemporal 16B stores (pure write stream, no reuse -> bypass cache).
// Wave-coalesced: lanes contiguous at every iteration (1 KiB / wave / store).
// ---------------------------------------------------------------------------
__global__ void __launch_bounds__(FILL_THREADS)
zero_fill(v4f* __restrict__ out) {
    const int tid = blockIdx.x * FILL_THREADS + threadIdx.x;
    const int stride = FILL_BLOCKS * FILL_THREADS;
    const v4f z = (v4f)(0.f);
    v4f* p = out + tid;
    #pragma unroll
    for (int k = 0; k < FILL_ITERS; ++k) {
        __builtin_nontemporal_store(z, p);
        p += stride;
    }
}

// ---------------------------------------------------------------------------
// Scatter the one-hot points. One thread per (b, c) pair, writing 4 planes:
// gen_poses[0], gen_poses[1] (sample-0 coords, replicated over B),
// step_poses[0], step_poses[1] (per-sample interpolated coords).
// All writes land at distinct addresses (each (plane,b,c) owns its own
// 256x256 slice), so no atomics needed. Stream order puts it after the fill.
// ---------------------------------------------------------------------------
__global__ void scatter_points(const float* __restrict__ pose1,
                               const float* __restrict__ pose2,
                               float* __restrict__ out) {
    int idx = blockIdx.x * blockDim.x + threadIdx.x;
    if (idx >= BB * CC) return;
    const int b = idx / CC;
    const int c = idx % CC;

    // ---- gen_poses: coords come from SAMPLE 0 for every b (reference quirk)
    {
        const float xf = pose1[(size_t)c * 2 + 0];
        const float yf = pose1[(size_t)c * 2 + 1];
        const int x = (int)truncf(xf);   // trunc toward zero, matches int()/jnp.trunc
        const int y = (int)truncf(yf);
        if (x >= 0 && x <= 255 && y >= 0 && y <= 255) {
            out[((size_t)(0 * BB + b) * CC + c) * HWSZ + (size_t)x * WW + y] = 1.0f;
        }
    }
    {
        const float xf = pose2[(size_t)c * 2 + 0];
        const float yf = pose2[(size_t)c * 2 + 1];
        const int x = (int)truncf(xf);
        const int y = (int)truncf(yf);
        if (x >= 0 && x <= 255 && y >= 0 && y <= 255) {
            out[((size_t)(1 * BB + b) * CC + c) * HWSZ + (size_t)x * WW + y] = 1.0f;
        }
    }

    // ---- step_poses: per-sample coords
    const float p1x = pose1[(size_t)idx * 2 + 0];
    const float p1y = pose1[(size_t)idx * 2 + 1];
    const float p2x = pose2[(size_t)idx * 2 + 0];
    const float p2y = pose2[(size_t)idx * 2 + 1];
    // jnp.floor_divide on floats == floor(x / y), computed in f32
    const float sx = floorf((p2x - p1x) / (float)NBLK);
    const float sy = floorf((p2y - p1y) / (float)NBLK);

    float cx = p1x + sx;   // sequential accumulation, same IEEE ops as ref
    float cy = p1y + sy;
    const size_t step_base = (size_t)2 * BB * CC * HWSZ;   // after gen_poses
    #pragma unroll
    for (int k = 0; k < NBLK - 1; ++k) {
        const int x = (int)truncf(cx);
        const int y = (int)truncf(cy);
        if (x >= 0 && x <= 255 && y >= 0 && y <= 255) {
            out[step_base + ((size_t)(k * BB + b) * CC + c) * HWSZ + (size_t)x * WW + y] = 1.0f;
        }
        cx += sx;
        cy += sy;
    }
}

extern "C" void kernel_launch(void* const* d_in, const int* in_sizes, int n_in,
                              void* d_out, int out_size, void* d_ws, size_t ws_size,
                              hipStream_t stream) {
    const float* pose1 = (const float*)d_in[0];   // [32, 18, 2] f32
    const float* pose2 = (const float*)d_in[1];   // [32, 18, 2] f32
    float* out = (float*)d_out;

    // out_size = 150,994,944 floats = FILL_BLOCKS*FILL_THREADS*FILL_ITERS v4f.
    zero_fill<<<FILL_BLOCKS, FILL_THREADS, 0, stream>>>((v4f*)out);

    const int npts = BB * CC;  // 576
    scatter_points<<<(npts + 255) / 256, 256, 0, stream>>>(pose1, pose2, out);
}

// Round 6
// 580.206 us; speedup vs baseline: 1.0728x; 1.0728x over previous
//
#include <hip/hip_runtime.h>

// Problem constants (match reference)
#define HH 256
#define WW 256
#define HWSZ (HH * WW)          // 65536 floats per plane
#define BB 32
#define CC 18
#define NBLK 3
#define NPLANES (4 * BB * CC)   // gen0 + gen1 + step0 + step1 = 2304 planes

typedef float v4f __attribute__((ext_vector_type(4)));

// ---------------------------------------------------------------------------
// Fused zero + scatter. One block per (outer, b, c) plane:
//   outer 0: gen_poses[0]  -> sample-0 coords from pose1 (reference quirk)
//   outer 1: gen_poses[1]  -> sample-0 coords from pose2
//   outer 2: step_poses[0] -> per-sample p1 + step
//   outer 3: step_poses[1] -> per-sample p1 + step + step
// Each block streams its 64 KB plane as zeros (256 thr x 64 float4, fully
// coalesced plain stores — NT measured slower in R5), then the one thread
// that owns the target float4 rewrites its element to 1.0 (same thread,
// same address, program order => no fence needed).
// ---------------------------------------------------------------------------
__global__ void __launch_bounds__(256)
fill_scatter(const float* __restrict__ pose1,
             const float* __restrict__ pose2,
             float* __restrict__ out) {
    const int plane = blockIdx.x;        // 0..2303
    const int outer = plane / (BB * CC);
    const int rem   = plane % (BB * CC); // b*CC + c
    const int c     = rem % CC;

    // ---- compute this plane's target coordinate (wave-uniform) ----
    float xf, yf;
    if (outer == 0) {
        xf = pose1[(size_t)c * 2 + 0];   // sample-0 coords, replicated over b
        yf = pose1[(size_t)c * 2 + 1];
    } else if (outer == 1) {
        xf = pose2[(size_t)c * 2 + 0];
        yf = pose2[(size_t)c * 2 + 1];
    } else {
        const float p1x = pose1[(size_t)rem * 2 + 0];
        const float p1y = pose1[(size_t)rem * 2 + 1];
        const float p2x = pose2[(size_t)rem * 2 + 0];
        const float p2y = pose2[(size_t)rem * 2 + 1];
        // jnp.floor_divide on floats == floor((p2-p1)/3), f32 IEEE ops
        const float sx = floorf((p2x - p1x) / (float)NBLK);
        const float sy = floorf((p2y - p1y) / (float)NBLK);
        // sequential accumulation, same IEEE op order as the reference
        xf = p1x + sx;
        yf = p1y + sy;
        if (outer == 3) { xf += sx; yf += sy; }
    }
    const int x = (int)truncf(xf);       // trunc toward zero == int()/jnp.trunc
    const int y = (int)truncf(yf);
    const bool valid = (x >= 0 && x <= 255 && y >= 0 && y <= 255);
    const int tgt = valid ? (x * WW + y) : -1;   // offset within plane, or -1

    // ---- stream the plane as zeros: 256 threads x 64 float4, coalesced ----
    float* plane_base = out + (size_t)plane * HWSZ;
    v4f* p4 = (v4f*)plane_base;
    const v4f z = (v4f)(0.f);
    const int t = threadIdx.x;
    #pragma unroll
    for (int k = 0; k < 64; ++k) {
        p4[k * 256 + t] = z;
    }

    // ---- one-hot write by the thread that owns the target float4 ----
    if (tgt >= 0 && t == ((tgt >> 2) & 255)) {
        plane_base[tgt] = 1.0f;
    }
}

extern "C" void kernel_launch(void* const* d_in, const int* in_sizes, int n_in,
                              void* d_out, int out_size, void* d_ws, size_t ws_size,
                              hipStream_t stream) {
    const float* pose1 = (const float*)d_in[0];   // [32, 18, 2] f32
    const float* pose2 = (const float*)d_in[1];   // [32, 18, 2] f32
    float* out = (float*)d_out;                   // [2,32,18,256,256] x2 concat

    // 2304 planes, one block each; out_size == NPLANES * HWSZ.
    fill_scatter<<<NPLANES, 256, 0, stream>>>(pose1, pose2, out);
}

// Round 7
// 567.577 us; speedup vs baseline: 1.0967x; 1.0223x over previous
//
#include <hip/hip_runtime.h>

// Problem constants (match reference)
#define HH 256
#define WW 256
#define HWSZ (HH * WW)
#define BB 32
#define CC 18
#define NBLK 3

// ---------------------------------------------------------------------------
// Structure (settled in R1-R6 exploration):
//   1. hipMemsetAsync zeroes the whole 604 MB output. This rides the rocclr
//      fillBufferAligned path, measured at 6.26 TB/s (78% of peak) — faster
//      than every source-level fill tried (grid-stride 2.8, NT 4.0,
//      plane-per-block 5.5 TB/s). 604 MB / 6.26 TB/s = 96 us, the floor.
//   2. scatter_points writes the <=2304 one-hot elements (~5 us).
// Remaining timed-window cost (~475 us) is the harness's own 0xAA poison
// fills of d_ws (2.416 GB) + d_out (604 MB), which are inside the graph
// replay window and not controllable from kernel_launch.
// ---------------------------------------------------------------------------

// Scatter the one-hot points. One thread per (b, c) pair, writing 4 planes:
// gen_poses[0], gen_poses[1] (sample-0 coords, replicated over B),
// step_poses[0], step_poses[1] (per-sample interpolated coords).
// All writes land at distinct addresses (each (plane,b,c) owns its own
// 256x256 slice), so no atomics needed. Stream order puts it after the zero.
__global__ void scatter_points(const float* __restrict__ pose1,
                               const float* __restrict__ pose2,
                               float* __restrict__ out) {
    int idx = blockIdx.x * blockDim.x + threadIdx.x;
    if (idx >= BB * CC) return;
    const int b = idx / CC;
    const int c = idx % CC;

    // ---- gen_poses: coords come from SAMPLE 0 for every b (reference quirk)
    {
        const float xf = pose1[(size_t)c * 2 + 0];
        const float yf = pose1[(size_t)c * 2 + 1];
        const int x = (int)truncf(xf);   // trunc toward zero == int()/jnp.trunc
        const int y = (int)truncf(yf);
        if (x >= 0 && x <= 255 && y >= 0 && y <= 255) {
            out[((size_t)(0 * BB + b) * CC + c) * HWSZ + (size_t)x * WW + y] = 1.0f;
        }
    }
    {
        const float xf = pose2[(size_t)c * 2 + 0];
        const float yf = pose2[(size_t)c * 2 + 1];
        const int x = (int)truncf(xf);
        const int y = (int)truncf(yf);
        if (x >= 0 && x <= 255 && y >= 0 && y <= 255) {
            out[((size_t)(1 * BB + b) * CC + c) * HWSZ + (size_t)x * WW + y] = 1.0f;
        }
    }

    // ---- step_poses: per-sample coords
    const float p1x = pose1[(size_t)idx * 2 + 0];
    const float p1y = pose1[(size_t)idx * 2 + 1];
    const float p2x = pose2[(size_t)idx * 2 + 0];
    const float p2y = pose2[(size_t)idx * 2 + 1];
    // jnp.floor_divide on floats == floor(x / y), computed in f32
    const float sx = floorf((p2x - p1x) / (float)NBLK);
    const float sy = floorf((p2y - p1y) / (float)NBLK);

    float cx = p1x + sx;   // sequential accumulation, same IEEE ops as ref
    float cy = p1y + sy;
    const size_t step_base = (size_t)2 * BB * CC * HWSZ;   // after gen_poses
    #pragma unroll
    for (int k = 0; k < NBLK - 1; ++k) {
        const int x = (int)truncf(cx);
        const int y = (int)truncf(cy);
        if (x >= 0 && x <= 255 && y >= 0 && y <= 255) {
            out[step_base + ((size_t)(k * BB + b) * CC + c) * HWSZ + (size_t)x * WW + y] = 1.0f;
        }
        cx += sx;
        cy += sy;
    }
}

extern "C" void kernel_launch(void* const* d_in, const int* in_sizes, int n_in,
                              void* d_out, int out_size, void* d_ws, size_t ws_size,
                              hipStream_t stream) {
    const float* pose1 = (const float*)d_in[0];   // [32, 18, 2] f32
    const float* pose2 = (const float*)d_in[1];   // [32, 18, 2] f32
    float* out = (float*)d_out;

    // Zero the whole 604 MB output via the rocclr fill path (6.26 TB/s).
    // Graph-capture-safe: async memset becomes a graph memset node.
    hipMemsetAsync(d_out, 0, (size_t)out_size * sizeof(float), stream);

    const int npts = BB * CC;  // 576
    scatter_points<<<(npts + 255) / 256, 256, 0, stream>>>(pose1, pose2, out);
}